// Round 1
// baseline (72143.549 us; speedup 1.0000x reference)
//
#include <hip/hip_runtime.h>
#include <hip/hip_bf16.h>
#include <hip/hip_cooperative_groups.h>

namespace cg = cooperative_groups;

typedef __bf16 bf16_t;
typedef bf16_t bf16x8 __attribute__((ext_vector_type(8)));
typedef float  f32x4  __attribute__((ext_vector_type(4)));

#define NB 64      // batch
#define NS 256     // seq len
#define NH 1024    // hidden
#define NL 4       // layers
#define G3H 3072   // 3*H

__device__ __forceinline__ f32x4 mfma16(bf16x8 a, bf16x8 b, f32x4 c) {
    return __builtin_amdgcn_mfma_f32_16x16x32_bf16(a, b, c, 0, 0, 0);
}

__device__ __forceinline__ float sigmoidf_(float x) {
    return 1.0f / (1.0f + expf(-x));
}

struct P {
    const float* x;        // (B,S,H)
    const float* b_ih;     // (L,3H)
    const float* b_hh;     // (L,3H)
    float* out;            // outs (B,S,H) then hT (L,B,H)
    const bf16_t* Wih;     // (L,3H,H)
    const bf16_t* Whh;
    const bf16_t* w0;      // (L,H,H)
    const bf16_t* w1;      // (L,512,512)
    const bf16_t* w2;      // (L,512,512)
    const bf16_t* w3;      // (L,H,2H)
    float*  h_fp;          // (L,B,H) hidden state fp32
    bf16_t* h_bf;          // (L,B,H)
    float*  hprime;        // (L,B,H) GRU output pre-attn
    bf16_t* se;            // (L,B,2,H)  row0=h', row1=sorted(h')
    bf16_t* sA0;           // (L,B,2048) shuffled a0
    bf16_t* sA1;           // (L,B,2048) shuffled a1
    bf16_t* a2;            // (L,B,2048) relu(a2) flat
    bf16_t* outbuf;        // (2,L,B,H)  inter-layer input, dbuf by t parity
};

struct ConvArgs {
    const float* src[6];
    bf16_t* dst[6];
    long n[6];
    const float* hidden0;  // (L,1,H)
    float* h_fp;
    bf16_t* h_bf;
};

__global__ void __launch_bounds__(256) convert_kernel(ConvArgs a) {
    const long tid = (long)blockIdx.x * 256 + threadIdx.x;
    const long stride = (long)gridDim.x * 256;
    for (int i = 0; i < 6; ++i) {
        const float* s = a.src[i];
        bf16_t* d = a.dst[i];
        const long n = a.n[i];
        for (long j = tid * 4; j < n; j += stride * 4) {
            float4 v = *(const float4*)(s + j);
            d[j + 0] = (bf16_t)v.x;
            d[j + 1] = (bf16_t)v.y;
            d[j + 2] = (bf16_t)v.z;
            d[j + 3] = (bf16_t)v.w;
        }
    }
    for (long j = tid; j < (long)NL * NB * NH; j += stride) {
        int l = (int)(j >> 16);           // B*H = 65536
        int c = (int)(j & (NH - 1));
        float v = a.hidden0[l * NH + c];
        a.h_fp[j] = v;
        a.h_bf[j] = (bf16_t)v;
    }
}

// ---------- S1: GRU. 8 waves: waves 0-3 = ih GEMM, waves 4-7 = hh GEMM,
//             hh partials passed through LDS, gates computed by ih waves ----------
__device__ __forceinline__ void st_gru(const P& p, int s, float* smem) {
    const int l = blockIdx.x >> 6;
    const int t = s - l;
    if (t < 0 || t >= NS) return;
    const int wj = blockIdx.x & 63;
    const int tid = threadIdx.x;
    const int wave = tid >> 6, lane = tid & 63;
    const int half = wave >> 2, ws = wave & 3;   // half: 0=ih, 1=hh; ws = batch stripe
    const int lane15 = lane & 15, quad = lane >> 4, kq = quad * 8;

    const int c0 = wj * 16;          // hidden column block
    const int m0 = ws * 16;          // batch row stripe
    const int arow = m0 + lane15;

    const bf16_t* W = (half ? p.Whh : p.Wih) + (size_t)l * G3H * NH;
    const bf16_t* brow0 = W + (size_t)(0 * NH + c0 + lane15) * NH;
    const bf16_t* brow1 = W + (size_t)(1 * NH + c0 + lane15) * NH;
    const bf16_t* brow2 = W + (size_t)(2 * NH + c0 + lane15) * NH;

    f32x4 acc0 = {}, acc1 = {}, acc2 = {};

    if (half == 0 && l == 0) {
        const float* xrow = p.x + ((size_t)arow * NS + t) * NH;
        for (int k0 = 0; k0 < NH; k0 += 32) {
            const int k = k0 + kq;
            float4 f0 = *(const float4*)(xrow + k);
            float4 f1 = *(const float4*)(xrow + k + 4);
            bf16x8 a;
            a[0] = (bf16_t)f0.x; a[1] = (bf16_t)f0.y;
            a[2] = (bf16_t)f0.z; a[3] = (bf16_t)f0.w;
            a[4] = (bf16_t)f1.x; a[5] = (bf16_t)f1.y;
            a[6] = (bf16_t)f1.z; a[7] = (bf16_t)f1.w;
            acc0 = mfma16(a, *(const bf16x8*)(brow0 + k), acc0);
            acc1 = mfma16(a, *(const bf16x8*)(brow1 + k), acc1);
            acc2 = mfma16(a, *(const bf16x8*)(brow2 + k), acc2);
        }
    } else {
        const bf16_t* ap = half
            ? (p.h_bf + (size_t)l * NB * NH + (size_t)arow * NH)
            : (p.outbuf + ((size_t)(t & 1) * NL + (l - 1)) * NB * NH + (size_t)arow * NH);
        for (int k0 = 0; k0 < NH; k0 += 32) {
            const int k = k0 + kq;
            bf16x8 a = *(const bf16x8*)(ap + k);
            acc0 = mfma16(a, *(const bf16x8*)(brow0 + k), acc0);
            acc1 = mfma16(a, *(const bf16x8*)(brow1 + k), acc1);
            acc2 = mfma16(a, *(const bf16x8*)(brow2 + k), acc2);
        }
    }

    if (half == 1) {
        // hand hh partials to the matching ih wave: layout [ws][g][lane][i]
        float* sl = smem + ws * 768 + lane * 4;
#pragma unroll
        for (int i = 0; i < 4; ++i) {
            sl[i]       = acc0[i];
            sl[256 + i] = acc1[i];
            sl[512 + i] = acc2[i];
        }
    }
    __syncthreads();
    if (half == 0) {
        const float* bih_l = p.b_ih + l * G3H;
        const float* bhh_l = p.b_hh + l * G3H;
        const float* hfp_l = p.h_fp + (size_t)l * NB * NH;
        float*  hpr_l = p.hprime + (size_t)l * NB * NH;
        bf16_t* se_l  = p.se + (size_t)l * 2 * NB * NH;
        const int c = c0 + lane15;
        const float* sl = smem + ws * 768 + lane * 4;
        const float b0 = bih_l[c], b1 = bih_l[NH + c], b2 = bih_l[2 * NH + c];
        const float d0 = bhh_l[c], d1 = bhh_l[NH + c], d2 = bhh_l[2 * NH + c];
#pragma unroll
        for (int i = 0; i < 4; ++i) {
            const int m = m0 + quad * 4 + i;
            float ir  = acc0[i] + b0;
            float iz  = acc1[i] + b1;
            float inn = acc2[i] + b2;
            float hr  = sl[i]       + d0;
            float hz  = sl[256 + i] + d1;
            float hn  = sl[512 + i] + d2;
            float r = sigmoidf_(ir + hr);
            float z = sigmoidf_(iz + hz);
            float n = tanhf(inn + r * hn);
            float hprev = hfp_l[(size_t)m * NH + c];
            float hp = (1.0f - z) * n + z * hprev;
            hpr_l[(size_t)m * NH + c] = hp;
            se_l[(size_t)(m * 2) * NH + c] = (bf16_t)hp;   // se row 0 = h'
        }
    }
}

// ---------- S2: sort h' rows (bitonic ascending) -> se row 1. 512 threads ----------
__device__ __forceinline__ void st_sort(const P& p, int s, float* smem) {
    const int l = blockIdx.x >> 6;
    const int t = s - l;
    if (t < 0 || t >= NS) return;
    const int b = blockIdx.x & 63;
    const int tid = threadIdx.x;
    const float* src = p.hprime + (size_t)l * NB * NH + (size_t)b * NH;
    for (int i = tid; i < NH; i += 512) smem[i] = src[i];
    __syncthreads();
    for (int kk = 2; kk <= NH; kk <<= 1) {
        for (int j = kk >> 1; j > 0; j >>= 1) {
#pragma unroll
            for (int bb = 0; bb < 2; ++bb) {
                const int i = bb * 512 + tid;
                const int ixj = i ^ j;
                if (ixj > i) {
                    float va = smem[i], vb = smem[ixj];
                    bool up = ((i & kk) == 0);
                    if (up ? (va > vb) : (va < vb)) {
                        smem[i] = vb; smem[ixj] = va;
                    }
                }
            }
            __syncthreads();
        }
    }
    bf16_t* dst = p.se + (size_t)l * 2 * NB * NH + (size_t)(b * 2 + 1) * NH;
    for (int i = tid; i < NH; i += 512) dst[i] = (bf16_t)smem[i];
}

// ---------- S3: a0 = se@w0^T (M=128,N=1024,K=1024). 8 waves cover all 128 rows ----------
__device__ __forceinline__ void st_a0(const P& p, int s) {
    const int l = blockIdx.x >> 6;
    const int t = s - l;
    if (t < 0 || t >= NS) return;
    const int cj = blockIdx.x & 63;      // 64 col jobs of 16
    const int tid = threadIdx.x;
    const int wave = tid >> 6, lane = tid & 63;
    const int lane15 = lane & 15, quad = lane >> 4, kq = quad * 8;
    const bf16_t* w0_l = p.w0 + (size_t)l * NH * NH;
    const bf16_t* se_l = p.se + (size_t)l * 2 * NB * NH;
    bf16_t* sA0_l = p.sA0 + (size_t)l * NB * 2048;

    const int c0 = cj * 16;
    const int r0 = wave * 16;            // 8 waves x 16 = 128 rows
    const bf16_t* arow = se_l + (size_t)(r0 + lane15) * NH;
    const bf16_t* brow = w0_l + (size_t)(c0 + lane15) * NH;
    f32x4 acc = {};
    for (int k0 = 0; k0 < NH; k0 += 32) {
        const int k = k0 + kq;
        acc = mfma16(*(const bf16x8*)(arow + k), *(const bf16x8*)(brow + k), acc);
    }
#pragma unroll
    for (int i = 0; i < 4; ++i) {
        const int r = r0 + quad * 4 + i;   // 0..127 = b*2+tt
        const int bidx = r >> 1, tt = r & 1;
        const int j0 = tt * NH + c0 + lane15;
        sA0_l[(size_t)bidx * 2048 + ((j0 & 511) * 4 + (j0 >> 9))] = (bf16_t)acc[i];
    }
}

// ---------- S4: a1 = sA0@w1^T (M=256,N=512,K=512). jobs = mhalf(2) x 32 cols ----------
__device__ __forceinline__ void st_a1(const P& p, int s) {
    const int l = blockIdx.x >> 6;
    const int t = s - l;
    if (t < 0 || t >= NS) return;
    const int wj = blockIdx.x & 63;
    const int tid = threadIdx.x;
    const int wave = tid >> 6, lane = tid & 63;
    const int lane15 = lane & 15, quad = lane >> 4, kq = quad * 8;
    const bf16_t* w1_l = p.w1 + (size_t)l * 512 * 512;
    const bf16_t* sA0_l = p.sA0 + (size_t)l * NB * 2048;
    bf16_t* sA1_l = p.sA1 + (size_t)l * NB * 2048;

    const int mhalf = wj >> 5;           // 0..1 -> rows 0-127 / 128-255
    const int c0 = (wj & 31) * 16;       // 32 col jobs of 16
    const int r0 = mhalf * 128 + wave * 16;
    const bf16_t* arow = sA0_l + (size_t)(r0 + lane15) * 512;
    const bf16_t* brow = w1_l + (size_t)(c0 + lane15) * 512;
    f32x4 acc = {};
    for (int k0 = 0; k0 < 512; k0 += 32) {
        const int k = k0 + kq;
        acc = mfma16(*(const bf16x8*)(arow + k), *(const bf16x8*)(brow + k), acc);
    }
#pragma unroll
    for (int i = 0; i < 4; ++i) {
        const int rr = r0 + quad * 4 + i;
        const int bidx = rr >> 2, g = rr & 3;
        const int o0 = c0 + lane15;
        sA1_l[(size_t)bidx * 2048 + o0 * 4 + g] = (bf16_t)acc[i];
    }
}

// ---------- S5: a2 = relu(sA1@w2^T), store flat ----------
__device__ __forceinline__ void st_a2(const P& p, int s) {
    const int l = blockIdx.x >> 6;
    const int t = s - l;
    if (t < 0 || t >= NS) return;
    const int wj = blockIdx.x & 63;
    const int tid = threadIdx.x;
    const int wave = tid >> 6, lane = tid & 63;
    const int lane15 = lane & 15, quad = lane >> 4, kq = quad * 8;
    const bf16_t* w2_l = p.w2 + (size_t)l * 512 * 512;
    const bf16_t* sA1_l = p.sA1 + (size_t)l * NB * 2048;
    bf16_t* a2_l = p.a2 + (size_t)l * NB * 2048;

    const int mhalf = wj >> 5;
    const int c0 = (wj & 31) * 16;
    const int r0 = mhalf * 128 + wave * 16;
    const bf16_t* arow = sA1_l + (size_t)(r0 + lane15) * 512;
    const bf16_t* brow = w2_l + (size_t)(c0 + lane15) * 512;
    f32x4 acc = {};
    for (int k0 = 0; k0 < 512; k0 += 32) {
        const int k = k0 + kq;
        acc = mfma16(*(const bf16x8*)(arow + k), *(const bf16x8*)(brow + k), acc);
    }
#pragma unroll
    for (int i = 0; i < 4; ++i) {
        const int rr = r0 + quad * 4 + i;       // b*4+g
        const int o0 = c0 + lane15;
        float v = acc[i] > 0.0f ? acc[i] : 0.0f;
        a2_l[(size_t)rr * 512 + o0] = (bf16_t)v;
    }
}

// ---------- S6: a3 = a2@w3^T (M=64,N=1024,K=2048); K split across wave groups,
//             combine via LDS; h = h'*sigmoid(a3) ----------
__device__ __forceinline__ void st_a3(const P& p, int s, float* smem) {
    const int l = blockIdx.x >> 6;
    const int t = s - l;
    if (t < 0 || t >= NS) return;
    const int wj = blockIdx.x & 63;
    const int tid = threadIdx.x;
    const int wave = tid >> 6, lane = tid & 63;
    const int kg = wave >> 2, ws = wave & 3;   // kg: K half; ws: batch stripe
    const int lane15 = lane & 15, quad = lane >> 4, kq = quad * 8;
    const bf16_t* w3_l = p.w3 + (size_t)l * NH * 2048;
    const bf16_t* a2_l = p.a2 + (size_t)l * NB * 2048;

    const int c0 = wj * 16;
    const int m0 = ws * 16;
    const int kb = kg * 1024;
    const bf16_t* arow = a2_l + (size_t)(m0 + lane15) * 2048 + kb;
    const bf16_t* brow = w3_l + (size_t)(c0 + lane15) * 2048 + kb;
    f32x4 acc = {};
    for (int k0 = 0; k0 < 1024; k0 += 32) {
        const int k = k0 + kq;
        acc = mfma16(*(const bf16x8*)(arow + k), *(const bf16x8*)(brow + k), acc);
    }
    if (kg == 1) {
        float* sl = smem + (ws * 64 + lane) * 4;
#pragma unroll
        for (int i = 0; i < 4; ++i) sl[i] = acc[i];
    }
    __syncthreads();
    if (kg == 0) {
        const float* hpr_l = p.hprime + (size_t)l * NB * NH;
        float*  hfp_l = p.h_fp + (size_t)l * NB * NH;
        bf16_t* hbf_l = p.h_bf + (size_t)l * NB * NH;
        const float* sl = smem + (ws * 64 + lane) * 4;
        const int c = c0 + lane15;
        bf16_t* ob = (l < NL - 1)
            ? (p.outbuf + ((size_t)(t & 1) * NL + l) * NB * NH) : nullptr;
#pragma unroll
        for (int i = 0; i < 4; ++i) {
            const int m = m0 + quad * 4 + i;
            float v = acc[i] + sl[i];
            float sg = sigmoidf_(v);
            float val = hpr_l[(size_t)m * NH + c] * sg;
            hfp_l[(size_t)m * NH + c] = val;
            hbf_l[(size_t)m * NH + c] = (bf16_t)val;
            if (l < NL - 1) {
                ob[(size_t)m * NH + c] = (bf16_t)val;
            } else {
                p.out[((size_t)m * NS + t) * NH + c] = val;   // outs (B,S,H)
            }
            if (t == NS - 1) {
                p.out[(size_t)NB * NS * NH + ((size_t)l * NB + m) * NH + c] = val;  // hT
            }
        }
    }
}

// ---------- persistent cooperative kernel: whole time loop, 6 grid syncs/step ----------
__global__ void __launch_bounds__(512) fused_kernel(P p) {
    __shared__ float smem[3072];   // gru combine (12KB) / sort buf (4KB) / a3 combine (4KB)
    cg::grid_group grid = cg::this_grid();
    for (int s = 0; s < NS + NL - 1; ++s) {
        st_gru(p, s, smem);   grid.sync();
        st_sort(p, s, smem);  grid.sync();
        st_a0(p, s);          grid.sync();
        st_a1(p, s);          grid.sync();
        st_a2(p, s);          grid.sync();
        st_a3(p, s, smem);    grid.sync();
    }
}

extern "C" void kernel_launch(void* const* d_in, const int* in_sizes, int n_in,
                              void* d_out, int out_size, void* d_ws, size_t ws_size,
                              hipStream_t stream) {
    const float* x       = (const float*)d_in[0];
    const float* hidden0 = (const float*)d_in[1];
    const float* Wih_f   = (const float*)d_in[2];
    const float* Whh_f   = (const float*)d_in[3];
    const float* bih     = (const float*)d_in[4];
    const float* bhh     = (const float*)d_in[5];
    const float* aw0     = (const float*)d_in[6];
    const float* aw1     = (const float*)d_in[7];
    const float* aw2     = (const float*)d_in[8];
    const float* aw3     = (const float*)d_in[9];

    char* ws = (char*)d_ws;
    size_t off = 0;
    auto alloc = [&](size_t bytes) -> void* {
        void* r = ws + off;
        off = (off + bytes + 255) & ~(size_t)255;
        return r;
    };

    const long nWih = (long)NL * G3H * NH;
    const long nWhh = (long)NL * G3H * NH;
    const long nw0  = (long)NL * NH * NH;
    const long nw1  = (long)NL * 512 * 512;
    const long nw2  = (long)NL * 512 * 512;
    const long nw3  = (long)NL * NH * 2048;

    P p;
    p.x = x; p.b_ih = bih; p.b_hh = bhh; p.out = (float*)d_out;
    p.Wih = (bf16_t*)alloc((size_t)nWih * 2);
    p.Whh = (bf16_t*)alloc((size_t)nWhh * 2);
    p.w0  = (bf16_t*)alloc((size_t)nw0 * 2);
    p.w1  = (bf16_t*)alloc((size_t)nw1 * 2);
    p.w2  = (bf16_t*)alloc((size_t)nw2 * 2);
    p.w3  = (bf16_t*)alloc((size_t)nw3 * 2);
    p.h_fp   = (float*) alloc((size_t)NL * NB * NH * 4);
    p.h_bf   = (bf16_t*)alloc((size_t)NL * NB * NH * 2);
    p.hprime = (float*) alloc((size_t)NL * NB * NH * 4);
    p.se     = (bf16_t*)alloc((size_t)NL * 2 * NB * NH * 2);
    p.sA0    = (bf16_t*)alloc((size_t)NL * NB * 2048 * 2);
    p.sA1    = (bf16_t*)alloc((size_t)NL * NB * 2048 * 2);
    p.a2     = (bf16_t*)alloc((size_t)NL * NB * 2048 * 2);
    p.outbuf = (bf16_t*)alloc((size_t)2 * NL * NB * NH * 2);

    ConvArgs ca;
    ca.src[0] = Wih_f; ca.dst[0] = (bf16_t*)p.Wih; ca.n[0] = nWih;
    ca.src[1] = Whh_f; ca.dst[1] = (bf16_t*)p.Whh; ca.n[1] = nWhh;
    ca.src[2] = aw0;   ca.dst[2] = (bf16_t*)p.w0;  ca.n[2] = nw0;
    ca.src[3] = aw1;   ca.dst[3] = (bf16_t*)p.w1;  ca.n[3] = nw1;
    ca.src[4] = aw2;   ca.dst[4] = (bf16_t*)p.w2;  ca.n[4] = nw2;
    ca.src[5] = aw3;   ca.dst[5] = (bf16_t*)p.w3;  ca.n[5] = nw3;
    ca.hidden0 = hidden0;
    ca.h_fp = p.h_fp;
    ca.h_bf = p.h_bf;

    convert_kernel<<<dim3(2048), dim3(256), 0, stream>>>(ca);

    void* kargs[] = { (void*)&p };
    hipLaunchCooperativeKernel((const void*)fused_kernel, dim3(256), dim3(512),
                               kargs, 0, stream);
}

// Round 2
// 44439.706 us; speedup vs baseline: 1.6234x; 1.6234x over previous
//
#include <hip/hip_runtime.h>
#include <hip/hip_bf16.h>

typedef __bf16 bf16_t;
typedef bf16_t bf16x8 __attribute__((ext_vector_type(8)));
typedef float  f32x4  __attribute__((ext_vector_type(4)));

#define NB 64      // batch
#define NS 256     // seq len
#define NH 1024    // hidden
#define NL 4       // layers
#define G3H 3072   // 3*H
#define NWG 256    // workgroups in the persistent grid

__device__ __forceinline__ f32x4 mfma16(bf16x8 a, bf16x8 b, f32x4 c) {
    return __builtin_amdgcn_mfma_f32_16x16x32_bf16(a, b, c, 0, 0, 0);
}

__device__ __forceinline__ float sigmoidf_(float x) {
    return 1.0f / (1.0f + expf(-x));
}

struct P {
    const float* x;        // (B,S,H)
    const float* b_ih;     // (L,3H)
    const float* b_hh;     // (L,3H)
    float* out;            // outs (B,S,H) then hT (L,B,H)
    const bf16_t* Wih;     // (L,3H,H)
    const bf16_t* Whh;
    const bf16_t* w0;      // (L,H,H)
    const bf16_t* w1;      // (L,512,512)
    const bf16_t* w2;      // (L,512,512)
    const bf16_t* w3;      // (L,H,2H)
    float*  h_fp;          // (L,B,H) hidden state fp32
    bf16_t* h_bf;          // (L,B,H)
    float*  hprime;        // (L,B,H) GRU output pre-attn
    bf16_t* se;            // (L,B,2,H)  row0=h', row1=sorted(h')
    bf16_t* sA0;           // (L,B,2048) shuffled a0
    bf16_t* sA1;           // (L,B,2048) shuffled a1
    bf16_t* a2;            // (L,B,2048) relu(a2) flat
    bf16_t* outbuf;        // (2,L,B,H)  inter-layer input, dbuf by t parity
    unsigned* bar;         // monotonic barrier counter (zeroed pre-launch)
};

struct ConvArgs {
    const float* src[6];
    bf16_t* dst[6];
    long n[6];
    const float* hidden0;  // (L,1,H)
    float* h_fp;
    bf16_t* h_bf;
    unsigned* bar;
};

__global__ void __launch_bounds__(256) convert_kernel(ConvArgs a) {
    const long tid = (long)blockIdx.x * 256 + threadIdx.x;
    const long stride = (long)gridDim.x * 256;
    if (tid == 0) *a.bar = 0u;   // reset barrier counter every launch/replay
    for (int i = 0; i < 6; ++i) {
        const float* s = a.src[i];
        bf16_t* d = a.dst[i];
        const long n = a.n[i];
        for (long j = tid * 4; j < n; j += stride * 4) {
            float4 v = *(const float4*)(s + j);
            d[j + 0] = (bf16_t)v.x;
            d[j + 1] = (bf16_t)v.y;
            d[j + 2] = (bf16_t)v.z;
            d[j + 3] = (bf16_t)v.w;
        }
    }
    for (long j = tid; j < (long)NL * NB * NH; j += stride) {
        int l = (int)(j >> 16);           // B*H = 65536
        int c = (int)(j & (NH - 1));
        float v = a.hidden0[l * NH + c];
        a.h_fp[j] = v;
        a.h_bf[j] = (bf16_t)v;
    }
}

// ---------- lightweight device-wide barrier (monotonic counter, no reset race) ----------
__device__ __forceinline__ void gbar(unsigned* bar, unsigned target) {
    __syncthreads();                       // all WG stores drained to L2 (per-wave vmcnt)
    if (threadIdx.x == 0) {
        __builtin_amdgcn_fence(__ATOMIC_RELEASE, "agent");   // L2 -> coherence point
        __hip_atomic_fetch_add(bar, 1u, __ATOMIC_RELAXED, __HIP_MEMORY_SCOPE_AGENT);
        while (__hip_atomic_load(bar, __ATOMIC_RELAXED, __HIP_MEMORY_SCOPE_AGENT) < target) {
            __builtin_amdgcn_s_sleep(2);
        }
        __builtin_amdgcn_fence(__ATOMIC_ACQUIRE, "agent");   // invalidate stale lines
    }
    __syncthreads();
}

// ---------- S1: GRU. 8 waves: waves 0-3 = ih GEMM, waves 4-7 = hh GEMM,
//             hh partials passed through LDS, gates computed by ih waves ----------
__device__ __forceinline__ void st_gru(const P& p, int s, float* smem) {
    const int l = blockIdx.x >> 6;
    const int t = s - l;
    if (t < 0 || t >= NS) return;
    const int wj = blockIdx.x & 63;
    const int tid = threadIdx.x;
    const int wave = tid >> 6, lane = tid & 63;
    const int half = wave >> 2, ws = wave & 3;   // half: 0=ih, 1=hh; ws = batch stripe
    const int lane15 = lane & 15, quad = lane >> 4, kq = quad * 8;

    const int c0 = wj * 16;          // hidden column block
    const int m0 = ws * 16;          // batch row stripe
    const int arow = m0 + lane15;

    const bf16_t* W = (half ? p.Whh : p.Wih) + (size_t)l * G3H * NH;
    const bf16_t* brow0 = W + (size_t)(0 * NH + c0 + lane15) * NH;
    const bf16_t* brow1 = W + (size_t)(1 * NH + c0 + lane15) * NH;
    const bf16_t* brow2 = W + (size_t)(2 * NH + c0 + lane15) * NH;

    f32x4 acc0 = {}, acc1 = {}, acc2 = {};

    if (half == 0 && l == 0) {
        const float* xrow = p.x + ((size_t)arow * NS + t) * NH;
#pragma unroll 2
        for (int k0 = 0; k0 < NH; k0 += 32) {
            const int k = k0 + kq;
            float4 f0 = *(const float4*)(xrow + k);
            float4 f1 = *(const float4*)(xrow + k + 4);
            bf16x8 a;
            a[0] = (bf16_t)f0.x; a[1] = (bf16_t)f0.y;
            a[2] = (bf16_t)f0.z; a[3] = (bf16_t)f0.w;
            a[4] = (bf16_t)f1.x; a[5] = (bf16_t)f1.y;
            a[6] = (bf16_t)f1.z; a[7] = (bf16_t)f1.w;
            acc0 = mfma16(a, *(const bf16x8*)(brow0 + k), acc0);
            acc1 = mfma16(a, *(const bf16x8*)(brow1 + k), acc1);
            acc2 = mfma16(a, *(const bf16x8*)(brow2 + k), acc2);
        }
    } else {
        const bf16_t* ap = half
            ? (p.h_bf + (size_t)l * NB * NH + (size_t)arow * NH)
            : (p.outbuf + ((size_t)(t & 1) * NL + (l - 1)) * NB * NH + (size_t)arow * NH);
#pragma unroll 2
        for (int k0 = 0; k0 < NH; k0 += 32) {
            const int k = k0 + kq;
            bf16x8 a = *(const bf16x8*)(ap + k);
            acc0 = mfma16(a, *(const bf16x8*)(brow0 + k), acc0);
            acc1 = mfma16(a, *(const bf16x8*)(brow1 + k), acc1);
            acc2 = mfma16(a, *(const bf16x8*)(brow2 + k), acc2);
        }
    }

    if (half == 1) {
        // hand hh partials to the matching ih wave: layout [ws][g][lane][i]
        float* sl = smem + ws * 768 + lane * 4;
#pragma unroll
        for (int i = 0; i < 4; ++i) {
            sl[i]       = acc0[i];
            sl[256 + i] = acc1[i];
            sl[512 + i] = acc2[i];
        }
    }
    __syncthreads();
    if (half == 0) {
        const float* bih_l = p.b_ih + l * G3H;
        const float* bhh_l = p.b_hh + l * G3H;
        const float* hfp_l = p.h_fp + (size_t)l * NB * NH;
        float*  hpr_l = p.hprime + (size_t)l * NB * NH;
        bf16_t* se_l  = p.se + (size_t)l * 2 * NB * NH;
        const int c = c0 + lane15;
        const float* sl = smem + ws * 768 + lane * 4;
        const float b0 = bih_l[c], b1 = bih_l[NH + c], b2 = bih_l[2 * NH + c];
        const float d0 = bhh_l[c], d1 = bhh_l[NH + c], d2 = bhh_l[2 * NH + c];
#pragma unroll
        for (int i = 0; i < 4; ++i) {
            const int m = m0 + quad * 4 + i;
            float ir  = acc0[i] + b0;
            float iz  = acc1[i] + b1;
            float inn = acc2[i] + b2;
            float hr  = sl[i]       + d0;
            float hz  = sl[256 + i] + d1;
            float hn  = sl[512 + i] + d2;
            float r = sigmoidf_(ir + hr);
            float z = sigmoidf_(iz + hz);
            float n = tanhf(inn + r * hn);
            float hprev = hfp_l[(size_t)m * NH + c];
            float hp = (1.0f - z) * n + z * hprev;
            hpr_l[(size_t)m * NH + c] = hp;
            se_l[(size_t)(m * 2) * NH + c] = (bf16_t)hp;   // se row 0 = h'
        }
    }
}

// ---------- S2: sort h' rows (bitonic ascending) -> se row 1. 512 threads ----------
__device__ __forceinline__ void st_sort(const P& p, int s, float* smem) {
    const int l = blockIdx.x >> 6;
    const int t = s - l;
    if (t < 0 || t >= NS) return;
    const int b = blockIdx.x & 63;
    const int tid = threadIdx.x;
    const float* src = p.hprime + (size_t)l * NB * NH + (size_t)b * NH;
    for (int i = tid; i < NH; i += 512) smem[i] = src[i];
    __syncthreads();
    for (int kk = 2; kk <= NH; kk <<= 1) {
        for (int j = kk >> 1; j > 0; j >>= 1) {
#pragma unroll
            for (int bb = 0; bb < 2; ++bb) {
                const int i = bb * 512 + tid;
                const int ixj = i ^ j;
                if (ixj > i) {
                    float va = smem[i], vb = smem[ixj];
                    bool up = ((i & kk) == 0);
                    if (up ? (va > vb) : (va < vb)) {
                        smem[i] = vb; smem[ixj] = va;
                    }
                }
            }
            __syncthreads();
        }
    }
    bf16_t* dst = p.se + (size_t)l * 2 * NB * NH + (size_t)(b * 2 + 1) * NH;
    for (int i = tid; i < NH; i += 512) dst[i] = (bf16_t)smem[i];
}

// ---------- S3: a0 = se@w0^T (M=128,N=1024,K=1024). 8 waves cover all 128 rows ----------
__device__ __forceinline__ void st_a0(const P& p, int s) {
    const int l = blockIdx.x >> 6;
    const int t = s - l;
    if (t < 0 || t >= NS) return;
    const int cj = blockIdx.x & 63;      // 64 col jobs of 16
    const int tid = threadIdx.x;
    const int wave = tid >> 6, lane = tid & 63;
    const int lane15 = lane & 15, quad = lane >> 4, kq = quad * 8;
    const bf16_t* w0_l = p.w0 + (size_t)l * NH * NH;
    const bf16_t* se_l = p.se + (size_t)l * 2 * NB * NH;
    bf16_t* sA0_l = p.sA0 + (size_t)l * NB * 2048;

    const int c0 = cj * 16;
    const int r0 = wave * 16;            // 8 waves x 16 = 128 rows
    const bf16_t* arow = se_l + (size_t)(r0 + lane15) * NH;
    const bf16_t* brow = w0_l + (size_t)(c0 + lane15) * NH;
    f32x4 acc = {};
#pragma unroll 4
    for (int k0 = 0; k0 < NH; k0 += 32) {
        const int k = k0 + kq;
        acc = mfma16(*(const bf16x8*)(arow + k), *(const bf16x8*)(brow + k), acc);
    }
#pragma unroll
    for (int i = 0; i < 4; ++i) {
        const int r = r0 + quad * 4 + i;   // 0..127 = b*2+tt
        const int bidx = r >> 1, tt = r & 1;
        const int j0 = tt * NH + c0 + lane15;
        sA0_l[(size_t)bidx * 2048 + ((j0 & 511) * 4 + (j0 >> 9))] = (bf16_t)acc[i];
    }
}

// ---------- S4: a1 = sA0@w1^T (M=256,N=512,K=512). jobs = mhalf(2) x 32 cols ----------
__device__ __forceinline__ void st_a1(const P& p, int s) {
    const int l = blockIdx.x >> 6;
    const int t = s - l;
    if (t < 0 || t >= NS) return;
    const int wj = blockIdx.x & 63;
    const int tid = threadIdx.x;
    const int wave = tid >> 6, lane = tid & 63;
    const int lane15 = lane & 15, quad = lane >> 4, kq = quad * 8;
    const bf16_t* w1_l = p.w1 + (size_t)l * 512 * 512;
    const bf16_t* sA0_l = p.sA0 + (size_t)l * NB * 2048;
    bf16_t* sA1_l = p.sA1 + (size_t)l * NB * 2048;

    const int mhalf = wj >> 5;           // 0..1 -> rows 0-127 / 128-255
    const int c0 = (wj & 31) * 16;       // 32 col jobs of 16
    const int r0 = mhalf * 128 + wave * 16;
    const bf16_t* arow = sA0_l + (size_t)(r0 + lane15) * 512;
    const bf16_t* brow = w1_l + (size_t)(c0 + lane15) * 512;
    f32x4 acc = {};
#pragma unroll 4
    for (int k0 = 0; k0 < 512; k0 += 32) {
        const int k = k0 + kq;
        acc = mfma16(*(const bf16x8*)(arow + k), *(const bf16x8*)(brow + k), acc);
    }
#pragma unroll
    for (int i = 0; i < 4; ++i) {
        const int rr = r0 + quad * 4 + i;
        const int bidx = rr >> 2, g = rr & 3;
        const int o0 = c0 + lane15;
        sA1_l[(size_t)bidx * 2048 + o0 * 4 + g] = (bf16_t)acc[i];
    }
}

// ---------- S5: a2 = relu(sA1@w2^T), store flat ----------
__device__ __forceinline__ void st_a2(const P& p, int s) {
    const int l = blockIdx.x >> 6;
    const int t = s - l;
    if (t < 0 || t >= NS) return;
    const int wj = blockIdx.x & 63;
    const int tid = threadIdx.x;
    const int wave = tid >> 6, lane = tid & 63;
    const int lane15 = lane & 15, quad = lane >> 4, kq = quad * 8;
    const bf16_t* w2_l = p.w2 + (size_t)l * 512 * 512;
    const bf16_t* sA1_l = p.sA1 + (size_t)l * NB * 2048;
    bf16_t* a2_l = p.a2 + (size_t)l * NB * 2048;

    const int mhalf = wj >> 5;
    const int c0 = (wj & 31) * 16;
    const int r0 = mhalf * 128 + wave * 16;
    const bf16_t* arow = sA1_l + (size_t)(r0 + lane15) * 512;
    const bf16_t* brow = w2_l + (size_t)(c0 + lane15) * 512;
    f32x4 acc = {};
#pragma unroll 4
    for (int k0 = 0; k0 < 512; k0 += 32) {
        const int k = k0 + kq;
        acc = mfma16(*(const bf16x8*)(arow + k), *(const bf16x8*)(brow + k), acc);
    }
#pragma unroll
    for (int i = 0; i < 4; ++i) {
        const int rr = r0 + quad * 4 + i;       // b*4+g
        const int o0 = c0 + lane15;
        float v = acc[i] > 0.0f ? acc[i] : 0.0f;
        a2_l[(size_t)rr * 512 + o0] = (bf16_t)v;
    }
}

// ---------- S6: a3 = a2@w3^T (M=64,N=1024,K=2048); K split across wave groups,
//             combine via LDS; h = h'*sigmoid(a3) ----------
__device__ __forceinline__ void st_a3(const P& p, int s, float* smem) {
    const int l = blockIdx.x >> 6;
    const int t = s - l;
    if (t < 0 || t >= NS) return;
    const int wj = blockIdx.x & 63;
    const int tid = threadIdx.x;
    const int wave = tid >> 6, lane = tid & 63;
    const int kg = wave >> 2, ws = wave & 3;   // kg: K half; ws: batch stripe
    const int lane15 = lane & 15, quad = lane >> 4, kq = quad * 8;
    const bf16_t* w3_l = p.w3 + (size_t)l * NH * 2048;
    const bf16_t* a2_l = p.a2 + (size_t)l * NB * 2048;

    const int c0 = wj * 16;
    const int m0 = ws * 16;
    const int kb = kg * 1024;
    const bf16_t* arow = a2_l + (size_t)(m0 + lane15) * 2048 + kb;
    const bf16_t* brow = w3_l + (size_t)(c0 + lane15) * 2048 + kb;
    f32x4 acc = {};
#pragma unroll 4
    for (int k0 = 0; k0 < 1024; k0 += 32) {
        const int k = k0 + kq;
        acc = mfma16(*(const bf16x8*)(arow + k), *(const bf16x8*)(brow + k), acc);
    }
    if (kg == 1) {
        float* sl = smem + (ws * 64 + lane) * 4;
#pragma unroll
        for (int i = 0; i < 4; ++i) sl[i] = acc[i];
    }
    __syncthreads();
    if (kg == 0) {
        const float* hpr_l = p.hprime + (size_t)l * NB * NH;
        float*  hfp_l = p.h_fp + (size_t)l * NB * NH;
        bf16_t* hbf_l = p.h_bf + (size_t)l * NB * NH;
        const float* sl = smem + (ws * 64 + lane) * 4;
        const int c = c0 + lane15;
        bf16_t* ob = (l < NL - 1)
            ? (p.outbuf + ((size_t)(t & 1) * NL + l) * NB * NH) : nullptr;
#pragma unroll
        for (int i = 0; i < 4; ++i) {
            const int m = m0 + quad * 4 + i;
            float v = acc[i] + sl[i];
            float sg = sigmoidf_(v);
            float val = hpr_l[(size_t)m * NH + c] * sg;
            hfp_l[(size_t)m * NH + c] = val;
            hbf_l[(size_t)m * NH + c] = (bf16_t)val;
            if (l < NL - 1) {
                ob[(size_t)m * NH + c] = (bf16_t)val;
            } else {
                p.out[((size_t)m * NS + t) * NH + c] = val;   // outs (B,S,H)
            }
            if (t == NS - 1) {
                p.out[(size_t)NB * NS * NH + ((size_t)l * NB + m) * NH + c] = val;  // hT
            }
        }
    }
}

// ---------- persistent kernel: whole time loop, 6 custom barriers/step ----------
__global__ void __launch_bounds__(512) fused_kernel(P p) {
    __shared__ float smem[3072];   // gru combine (12KB) / sort buf (4KB) / a3 combine (4KB)
    unsigned r = 0;
    for (int s = 0; s < NS + NL - 1; ++s) {
        st_gru(p, s, smem);   r += NWG; gbar(p.bar, r);
        st_sort(p, s, smem);  r += NWG; gbar(p.bar, r);
        st_a0(p, s);          r += NWG; gbar(p.bar, r);
        st_a1(p, s);          r += NWG; gbar(p.bar, r);
        st_a2(p, s);          r += NWG; gbar(p.bar, r);
        st_a3(p, s, smem);    r += NWG; gbar(p.bar, r);
    }
}

extern "C" void kernel_launch(void* const* d_in, const int* in_sizes, int n_in,
                              void* d_out, int out_size, void* d_ws, size_t ws_size,
                              hipStream_t stream) {
    const float* x       = (const float*)d_in[0];
    const float* hidden0 = (const float*)d_in[1];
    const float* Wih_f   = (const float*)d_in[2];
    const float* Whh_f   = (const float*)d_in[3];
    const float* bih     = (const float*)d_in[4];
    const float* bhh     = (const float*)d_in[5];
    const float* aw0     = (const float*)d_in[6];
    const float* aw1     = (const float*)d_in[7];
    const float* aw2     = (const float*)d_in[8];
    const float* aw3     = (const float*)d_in[9];

    char* ws = (char*)d_ws;
    size_t off = 0;
    auto alloc = [&](size_t bytes) -> void* {
        void* r = ws + off;
        off = (off + bytes + 255) & ~(size_t)255;
        return r;
    };

    const long nWih = (long)NL * G3H * NH;
    const long nWhh = (long)NL * G3H * NH;
    const long nw0  = (long)NL * NH * NH;
    const long nw1  = (long)NL * 512 * 512;
    const long nw2  = (long)NL * 512 * 512;
    const long nw3  = (long)NL * NH * 2048;

    P p;
    p.x = x; p.b_ih = bih; p.b_hh = bhh; p.out = (float*)d_out;
    p.Wih = (bf16_t*)alloc((size_t)nWih * 2);
    p.Whh = (bf16_t*)alloc((size_t)nWhh * 2);
    p.w0  = (bf16_t*)alloc((size_t)nw0 * 2);
    p.w1  = (bf16_t*)alloc((size_t)nw1 * 2);
    p.w2  = (bf16_t*)alloc((size_t)nw2 * 2);
    p.w3  = (bf16_t*)alloc((size_t)nw3 * 2);
    p.h_fp   = (float*) alloc((size_t)NL * NB * NH * 4);
    p.h_bf   = (bf16_t*)alloc((size_t)NL * NB * NH * 2);
    p.hprime = (float*) alloc((size_t)NL * NB * NH * 4);
    p.se     = (bf16_t*)alloc((size_t)NL * 2 * NB * NH * 2);
    p.sA0    = (bf16_t*)alloc((size_t)NL * NB * 2048 * 2);
    p.sA1    = (bf16_t*)alloc((size_t)NL * NB * 2048 * 2);
    p.a2     = (bf16_t*)alloc((size_t)NL * NB * 2048 * 2);
    p.outbuf = (bf16_t*)alloc((size_t)2 * NL * NB * NH * 2);
    p.bar    = (unsigned*)alloc(256);

    ConvArgs ca;
    ca.src[0] = Wih_f; ca.dst[0] = (bf16_t*)p.Wih; ca.n[0] = nWih;
    ca.src[1] = Whh_f; ca.dst[1] = (bf16_t*)p.Whh; ca.n[1] = nWhh;
    ca.src[2] = aw0;   ca.dst[2] = (bf16_t*)p.w0;  ca.n[2] = nw0;
    ca.src[3] = aw1;   ca.dst[3] = (bf16_t*)p.w1;  ca.n[3] = nw1;
    ca.src[4] = aw2;   ca.dst[4] = (bf16_t*)p.w2;  ca.n[4] = nw2;
    ca.src[5] = aw3;   ca.dst[5] = (bf16_t*)p.w3;  ca.n[5] = nw3;
    ca.hidden0 = hidden0;
    ca.h_fp = p.h_fp;
    ca.h_bf = p.h_bf;
    ca.bar = p.bar;

    convert_kernel<<<dim3(2048), dim3(256), 0, stream>>>(ca);

    void* kargs[] = { (void*)&p };
    hipLaunchCooperativeKernel((const void*)fused_kernel, dim3(NWG), dim3(512),
                               kargs, 0, stream);
}

// Round 3
// 43052.148 us; speedup vs baseline: 1.6757x; 1.0322x over previous
//
#include <hip/hip_runtime.h>
#include <hip/hip_bf16.h>

typedef __bf16 bf16_t;
typedef bf16_t bf16x8 __attribute__((ext_vector_type(8)));
typedef float  f32x4  __attribute__((ext_vector_type(4)));

#define NB 64      // batch
#define NS 256     // seq len
#define NH 1024    // hidden
#define NL 4       // layers
#define G3H 3072   // 3*H
#define NWG 256    // workgroups in the persistent grid

__device__ __forceinline__ f32x4 mfma16(bf16x8 a, bf16x8 b, f32x4 c) {
    return __builtin_amdgcn_mfma_f32_16x16x32_bf16(a, b, c, 0, 0, 0);
}

__device__ __forceinline__ float sigmoidf_(float x) {
    return 1.0f / (1.0f + expf(-x));
}

struct P {
    const float* x;        // (B,S,H)
    const float* b_ih;     // (L,3H)
    const float* b_hh;     // (L,3H)
    float* out;            // outs (B,S,H) then hT (L,B,H)
    const bf16_t* Wih;     // (L,3H,H)
    const bf16_t* Whh;
    const bf16_t* w0;      // (L,H,H)
    const bf16_t* w1;      // (L,512,512)
    const bf16_t* w2;      // (L,512,512)
    const bf16_t* w3;      // (L,H,2H)
    float*  h_fp;          // (L,B,H) hidden state fp32
    bf16_t* h_bf;          // (L,B,H)
    float*  hprime;        // (L,B,H) GRU output pre-attn
    bf16_t* se;            // (L,B,2,H)  row0=h', row1=sorted(h')
    bf16_t* sA0;           // (L,B,2048) shuffled a0
    bf16_t* sA1;           // (L,B,2048) shuffled a1
    bf16_t* a2;            // (L,B,2048) relu(a2) flat
    bf16_t* outbuf;        // (2,L,B,H)  inter-layer input, dbuf by t parity
    unsigned* bar;         // barrier counters: 8 cachelines (stride 32 u32)
};

struct ConvArgs {
    const float* src[6];
    bf16_t* dst[6];
    long n[6];
    const float* hidden0;  // (L,1,H)
    float* h_fp;
    bf16_t* h_bf;
    unsigned* bar;
};

__global__ void __launch_bounds__(256) convert_kernel(ConvArgs a) {
    const long tid = (long)blockIdx.x * 256 + threadIdx.x;
    const long stride = (long)gridDim.x * 256;
    if (tid < 8) a.bar[tid * 32] = 0u;   // reset barrier lines every launch/replay
    for (int i = 0; i < 6; ++i) {
        const float* s = a.src[i];
        bf16_t* d = a.dst[i];
        const long n = a.n[i];
        for (long j = tid * 4; j < n; j += stride * 4) {
            float4 v = *(const float4*)(s + j);
            d[j + 0] = (bf16_t)v.x;
            d[j + 1] = (bf16_t)v.y;
            d[j + 2] = (bf16_t)v.z;
            d[j + 3] = (bf16_t)v.w;
        }
    }
    for (long j = tid; j < (long)NL * NB * NH; j += stride) {
        int l = (int)(j >> 16);           // B*H = 65536
        int c = (int)(j & (NH - 1));
        float v = a.hidden0[l * NH + c];
        a.h_fp[j] = v;
        a.h_bf[j] = (bf16_t)v;
    }
}

// ---------- device-wide barrier: 8-line split arrival (32 WGs/line), monotonic ----------
__device__ __forceinline__ void gbar(unsigned* bar, unsigned round) {
    __syncthreads();                       // WG done; stores drained to L2
    const int tid = threadIdx.x;
    if (tid == 0) {
        __builtin_amdgcn_fence(__ATOMIC_RELEASE, "agent");   // L2 writeback
        __hip_atomic_fetch_add(bar + (blockIdx.x & 7) * 32, 1u,
                               __ATOMIC_RELAXED, __HIP_MEMORY_SCOPE_AGENT);
    }
    if (tid < 8) {
        const unsigned tgt = round * 32;   // 256 WGs / 8 lines
        while (__hip_atomic_load(bar + tid * 32, __ATOMIC_RELAXED,
                                 __HIP_MEMORY_SCOPE_AGENT) < tgt) {
            __builtin_amdgcn_s_sleep(1);
        }
        __builtin_amdgcn_fence(__ATOMIC_ACQUIRE, "agent");   // invalidate stale lines
    }
    __syncthreads();
}

// ---------- S1: GRU. waves 0-3 = ih GEMM, waves 4-7 = hh GEMM; LDS combine ----------
__device__ __forceinline__ void st_gru(const P& p, int s, float* smem) {
    const int l = blockIdx.x >> 6;
    const int t = s - l;
    if (t < 0 || t >= NS) return;
    const int wj = blockIdx.x & 63;
    const int tid = threadIdx.x;
    const int wave = tid >> 6, lane = tid & 63;
    const int half = wave >> 2, ws = wave & 3;   // half: 0=ih, 1=hh; ws = batch stripe
    const int lane15 = lane & 15, quad = lane >> 4, kq = quad * 8;

    const int c0 = wj * 16;          // hidden column block
    const int m0 = ws * 16;          // batch row stripe
    const int arow = m0 + lane15;

    const bf16_t* W = (half ? p.Whh : p.Wih) + (size_t)l * G3H * NH;
    const bf16_t* brow0 = W + (size_t)(0 * NH + c0 + lane15) * NH;
    const bf16_t* brow1 = W + (size_t)(1 * NH + c0 + lane15) * NH;
    const bf16_t* brow2 = W + (size_t)(2 * NH + c0 + lane15) * NH;

    f32x4 acc0 = {}, acc1 = {}, acc2 = {};
    constexpr int PF = 4;

    if (half == 0 && l == 0) {
        const float* xrow = p.x + ((size_t)arow * NS + t) * NH;
        float4 fa[PF], fb[PF];
        bf16x8 b0b[PF], b1b[PF], b2b[PF];
#pragma unroll
        for (int pp = 0; pp < PF; ++pp) {
            const int k = pp * 32 + kq;
            fa[pp]  = *(const float4*)(xrow + k);
            fb[pp]  = *(const float4*)(xrow + k + 4);
            b0b[pp] = *(const bf16x8*)(brow0 + k);
            b1b[pp] = *(const bf16x8*)(brow1 + k);
            b2b[pp] = *(const bf16x8*)(brow2 + k);
        }
#pragma unroll
        for (int kk = 0; kk < 32; ++kk) {
            const int sl = kk & (PF - 1);
            float4 f0 = fa[sl], f1 = fb[sl];
            bf16x8 w0v = b0b[sl], w1v = b1b[sl], w2v = b2b[sl];
            if (kk + PF < 32) {
                const int k = (kk + PF) * 32 + kq;
                fa[sl]  = *(const float4*)(xrow + k);
                fb[sl]  = *(const float4*)(xrow + k + 4);
                b0b[sl] = *(const bf16x8*)(brow0 + k);
                b1b[sl] = *(const bf16x8*)(brow1 + k);
                b2b[sl] = *(const bf16x8*)(brow2 + k);
            }
            bf16x8 a;
            a[0] = (bf16_t)f0.x; a[1] = (bf16_t)f0.y;
            a[2] = (bf16_t)f0.z; a[3] = (bf16_t)f0.w;
            a[4] = (bf16_t)f1.x; a[5] = (bf16_t)f1.y;
            a[6] = (bf16_t)f1.z; a[7] = (bf16_t)f1.w;
            acc0 = mfma16(a, w0v, acc0);
            acc1 = mfma16(a, w1v, acc1);
            acc2 = mfma16(a, w2v, acc2);
        }
    } else {
        const bf16_t* ap = half
            ? (p.h_bf + (size_t)l * NB * NH + (size_t)arow * NH)
            : (p.outbuf + ((size_t)(t & 1) * NL + (l - 1)) * NB * NH + (size_t)arow * NH);
        bf16x8 ab[PF], b0b[PF], b1b[PF], b2b[PF];
#pragma unroll
        for (int pp = 0; pp < PF; ++pp) {
            const int k = pp * 32 + kq;
            ab[pp]  = *(const bf16x8*)(ap + k);
            b0b[pp] = *(const bf16x8*)(brow0 + k);
            b1b[pp] = *(const bf16x8*)(brow1 + k);
            b2b[pp] = *(const bf16x8*)(brow2 + k);
        }
#pragma unroll
        for (int kk = 0; kk < 32; ++kk) {
            const int sl = kk & (PF - 1);
            bf16x8 a = ab[sl], w0v = b0b[sl], w1v = b1b[sl], w2v = b2b[sl];
            if (kk + PF < 32) {
                const int k = (kk + PF) * 32 + kq;
                ab[sl]  = *(const bf16x8*)(ap + k);
                b0b[sl] = *(const bf16x8*)(brow0 + k);
                b1b[sl] = *(const bf16x8*)(brow1 + k);
                b2b[sl] = *(const bf16x8*)(brow2 + k);
            }
            acc0 = mfma16(a, w0v, acc0);
            acc1 = mfma16(a, w1v, acc1);
            acc2 = mfma16(a, w2v, acc2);
        }
    }

    if (half == 1) {
        // hand hh partials to the matching ih wave: layout [ws][g][lane][i]
        float* sl = smem + ws * 768 + lane * 4;
#pragma unroll
        for (int i = 0; i < 4; ++i) {
            sl[i]       = acc0[i];
            sl[256 + i] = acc1[i];
            sl[512 + i] = acc2[i];
        }
    }
    __syncthreads();
    if (half == 0) {
        const float* bih_l = p.b_ih + l * G3H;
        const float* bhh_l = p.b_hh + l * G3H;
        const float* hfp_l = p.h_fp + (size_t)l * NB * NH;
        float*  hpr_l = p.hprime + (size_t)l * NB * NH;
        bf16_t* se_l  = p.se + (size_t)l * 2 * NB * NH;
        const int c = c0 + lane15;
        const float* sl = smem + ws * 768 + lane * 4;
        const float b0 = bih_l[c], b1 = bih_l[NH + c], b2 = bih_l[2 * NH + c];
        const float d0 = bhh_l[c], d1 = bhh_l[NH + c], d2 = bhh_l[2 * NH + c];
#pragma unroll
        for (int i = 0; i < 4; ++i) {
            const int m = m0 + quad * 4 + i;
            float ir  = acc0[i] + b0;
            float iz  = acc1[i] + b1;
            float inn = acc2[i] + b2;
            float hr  = sl[i]       + d0;
            float hz  = sl[256 + i] + d1;
            float hn  = sl[512 + i] + d2;
            float r = sigmoidf_(ir + hr);
            float z = sigmoidf_(iz + hz);
            float n = tanhf(inn + r * hn);
            float hprev = hfp_l[(size_t)m * NH + c];
            float hp = (1.0f - z) * n + z * hprev;
            hpr_l[(size_t)m * NH + c] = hp;
            se_l[(size_t)(m * 2) * NH + c] = (bf16_t)hp;   // se row 0 = h'
        }
    }
}

// ---------- S2: sort h' rows (bitonic ascending) -> se row 1. 512 threads ----------
__device__ __forceinline__ void st_sort(const P& p, int s, float* smem) {
    const int l = blockIdx.x >> 6;
    const int t = s - l;
    if (t < 0 || t >= NS) return;
    const int b = blockIdx.x & 63;
    const int tid = threadIdx.x;
    const float* src = p.hprime + (size_t)l * NB * NH + (size_t)b * NH;
    for (int i = tid; i < NH; i += 512) smem[i] = src[i];
    __syncthreads();
    for (int kk = 2; kk <= NH; kk <<= 1) {
        for (int j = kk >> 1; j > 0; j >>= 1) {
#pragma unroll
            for (int bb = 0; bb < 2; ++bb) {
                const int i = bb * 512 + tid;
                const int ixj = i ^ j;
                if (ixj > i) {
                    float va = smem[i], vb = smem[ixj];
                    bool up = ((i & kk) == 0);
                    if (up ? (va > vb) : (va < vb)) {
                        smem[i] = vb; smem[ixj] = va;
                    }
                }
            }
            __syncthreads();
        }
    }
    bf16_t* dst = p.se + (size_t)l * 2 * NB * NH + (size_t)(b * 2 + 1) * NH;
    for (int i = tid; i < NH; i += 512) dst[i] = (bf16_t)smem[i];
}

// ---------- S3: a0 = se@w0^T (M=128,N=1024,K=1024). 8 waves cover all 128 rows ----------
__device__ __forceinline__ void st_a0(const P& p, int s) {
    const int l = blockIdx.x >> 6;
    const int t = s - l;
    if (t < 0 || t >= NS) return;
    const int cj = blockIdx.x & 63;      // 64 col jobs of 16
    const int tid = threadIdx.x;
    const int wave = tid >> 6, lane = tid & 63;
    const int lane15 = lane & 15, quad = lane >> 4, kq = quad * 8;
    const bf16_t* w0_l = p.w0 + (size_t)l * NH * NH;
    const bf16_t* se_l = p.se + (size_t)l * 2 * NB * NH;
    bf16_t* sA0_l = p.sA0 + (size_t)l * NB * 2048;

    const int c0 = cj * 16;
    const int r0 = wave * 16;            // 8 waves x 16 = 128 rows
    const bf16_t* arow = se_l + (size_t)(r0 + lane15) * NH;
    const bf16_t* brow = w0_l + (size_t)(c0 + lane15) * NH;
    constexpr int PF = 4;
    bf16x8 abuf[PF], bbuf[PF];
#pragma unroll
    for (int pp = 0; pp < PF; ++pp) {
        const int k = pp * 32 + kq;
        abuf[pp] = *(const bf16x8*)(arow + k);
        bbuf[pp] = *(const bf16x8*)(brow + k);
    }
    f32x4 acc = {};
#pragma unroll
    for (int kk = 0; kk < 32; ++kk) {
        const int sl = kk & (PF - 1);
        bf16x8 a = abuf[sl], b = bbuf[sl];
        if (kk + PF < 32) {
            const int k = (kk + PF) * 32 + kq;
            abuf[sl] = *(const bf16x8*)(arow + k);
            bbuf[sl] = *(const bf16x8*)(brow + k);
        }
        acc = mfma16(a, b, acc);
    }
#pragma unroll
    for (int i = 0; i < 4; ++i) {
        const int r = r0 + quad * 4 + i;   // 0..127 = b*2+tt
        const int bidx = r >> 1, tt = r & 1;
        const int j0 = tt * NH + c0 + lane15;
        sA0_l[(size_t)bidx * 2048 + ((j0 & 511) * 4 + (j0 >> 9))] = (bf16_t)acc[i];
    }
}

// ---------- S4: a1 = sA0@w1^T (M=256,N=512,K=512). jobs = mhalf(2) x 32 cols ----------
__device__ __forceinline__ void st_a1(const P& p, int s) {
    const int l = blockIdx.x >> 6;
    const int t = s - l;
    if (t < 0 || t >= NS) return;
    const int wj = blockIdx.x & 63;
    const int tid = threadIdx.x;
    const int wave = tid >> 6, lane = tid & 63;
    const int lane15 = lane & 15, quad = lane >> 4, kq = quad * 8;
    const bf16_t* w1_l = p.w1 + (size_t)l * 512 * 512;
    const bf16_t* sA0_l = p.sA0 + (size_t)l * NB * 2048;
    bf16_t* sA1_l = p.sA1 + (size_t)l * NB * 2048;

    const int mhalf = wj >> 5;           // 0..1 -> rows 0-127 / 128-255
    const int c0 = (wj & 31) * 16;       // 32 col jobs of 16
    const int r0 = mhalf * 128 + wave * 16;
    const bf16_t* arow = sA0_l + (size_t)(r0 + lane15) * 512;
    const bf16_t* brow = w1_l + (size_t)(c0 + lane15) * 512;
    constexpr int PF = 4;
    bf16x8 abuf[PF], bbuf[PF];
#pragma unroll
    for (int pp = 0; pp < PF; ++pp) {
        const int k = pp * 32 + kq;
        abuf[pp] = *(const bf16x8*)(arow + k);
        bbuf[pp] = *(const bf16x8*)(brow + k);
    }
    f32x4 acc = {};
#pragma unroll
    for (int kk = 0; kk < 16; ++kk) {
        const int sl = kk & (PF - 1);
        bf16x8 a = abuf[sl], b = bbuf[sl];
        if (kk + PF < 16) {
            const int k = (kk + PF) * 32 + kq;
            abuf[sl] = *(const bf16x8*)(arow + k);
            bbuf[sl] = *(const bf16x8*)(brow + k);
        }
        acc = mfma16(a, b, acc);
    }
#pragma unroll
    for (int i = 0; i < 4; ++i) {
        const int rr = r0 + quad * 4 + i;
        const int bidx = rr >> 2, g = rr & 3;
        const int o0 = c0 + lane15;
        sA1_l[(size_t)bidx * 2048 + o0 * 4 + g] = (bf16_t)acc[i];
    }
}

// ---------- S5: a2 = relu(sA1@w2^T), store flat ----------
__device__ __forceinline__ void st_a2(const P& p, int s) {
    const int l = blockIdx.x >> 6;
    const int t = s - l;
    if (t < 0 || t >= NS) return;
    const int wj = blockIdx.x & 63;
    const int tid = threadIdx.x;
    const int wave = tid >> 6, lane = tid & 63;
    const int lane15 = lane & 15, quad = lane >> 4, kq = quad * 8;
    const bf16_t* w2_l = p.w2 + (size_t)l * 512 * 512;
    const bf16_t* sA1_l = p.sA1 + (size_t)l * NB * 2048;
    bf16_t* a2_l = p.a2 + (size_t)l * NB * 2048;

    const int mhalf = wj >> 5;
    const int c0 = (wj & 31) * 16;
    const int r0 = mhalf * 128 + wave * 16;
    const bf16_t* arow = sA1_l + (size_t)(r0 + lane15) * 512;
    const bf16_t* brow = w2_l + (size_t)(c0 + lane15) * 512;
    constexpr int PF = 4;
    bf16x8 abuf[PF], bbuf[PF];
#pragma unroll
    for (int pp = 0; pp < PF; ++pp) {
        const int k = pp * 32 + kq;
        abuf[pp] = *(const bf16x8*)(arow + k);
        bbuf[pp] = *(const bf16x8*)(brow + k);
    }
    f32x4 acc = {};
#pragma unroll
    for (int kk = 0; kk < 16; ++kk) {
        const int sl = kk & (PF - 1);
        bf16x8 a = abuf[sl], b = bbuf[sl];
        if (kk + PF < 16) {
            const int k = (kk + PF) * 32 + kq;
            abuf[sl] = *(const bf16x8*)(arow + k);
            bbuf[sl] = *(const bf16x8*)(brow + k);
        }
        acc = mfma16(a, b, acc);
    }
#pragma unroll
    for (int i = 0; i < 4; ++i) {
        const int rr = r0 + quad * 4 + i;       // b*4+g
        const int o0 = c0 + lane15;
        float v = acc[i] > 0.0f ? acc[i] : 0.0f;
        a2_l[(size_t)rr * 512 + o0] = (bf16_t)v;
    }
}

// ---------- S6: a3 = a2@w3^T (M=64,N=1024,K=2048); K split across wave groups,
//             combine via LDS; h = h'*sigmoid(a3) ----------
__device__ __forceinline__ void st_a3(const P& p, int s, float* smem) {
    const int l = blockIdx.x >> 6;
    const int t = s - l;
    if (t < 0 || t >= NS) return;
    const int wj = blockIdx.x & 63;
    const int tid = threadIdx.x;
    const int wave = tid >> 6, lane = tid & 63;
    const int kg = wave >> 2, ws = wave & 3;   // kg: K half; ws: batch stripe
    const int lane15 = lane & 15, quad = lane >> 4, kq = quad * 8;
    const bf16_t* w3_l = p.w3 + (size_t)l * NH * 2048;
    const bf16_t* a2_l = p.a2 + (size_t)l * NB * 2048;

    const int c0 = wj * 16;
    const int m0 = ws * 16;
    const int kb = kg * 1024;
    const bf16_t* arow = a2_l + (size_t)(m0 + lane15) * 2048 + kb;
    const bf16_t* brow = w3_l + (size_t)(c0 + lane15) * 2048 + kb;
    constexpr int PF = 4;
    bf16x8 abuf[PF], bbuf[PF];
#pragma unroll
    for (int pp = 0; pp < PF; ++pp) {
        const int k = pp * 32 + kq;
        abuf[pp] = *(const bf16x8*)(arow + k);
        bbuf[pp] = *(const bf16x8*)(brow + k);
    }
    f32x4 acc = {};
#pragma unroll
    for (int kk = 0; kk < 32; ++kk) {
        const int sl = kk & (PF - 1);
        bf16x8 a = abuf[sl], b = bbuf[sl];
        if (kk + PF < 32) {
            const int k = (kk + PF) * 32 + kq;
            abuf[sl] = *(const bf16x8*)(arow + k);
            bbuf[sl] = *(const bf16x8*)(brow + k);
        }
        acc = mfma16(a, b, acc);
    }
    if (kg == 1) {
        float* sl = smem + (ws * 64 + lane) * 4;
#pragma unroll
        for (int i = 0; i < 4; ++i) sl[i] = acc[i];
    }
    __syncthreads();
    if (kg == 0) {
        const float* hpr_l = p.hprime + (size_t)l * NB * NH;
        float*  hfp_l = p.h_fp + (size_t)l * NB * NH;
        bf16_t* hbf_l = p.h_bf + (size_t)l * NB * NH;
        const float* sl = smem + (ws * 64 + lane) * 4;
        const int c = c0 + lane15;
        bf16_t* ob = (l < NL - 1)
            ? (p.outbuf + ((size_t)(t & 1) * NL + l) * NB * NH) : nullptr;
#pragma unroll
        for (int i = 0; i < 4; ++i) {
            const int m = m0 + quad * 4 + i;
            float v = acc[i] + sl[i];
            float sg = sigmoidf_(v);
            float val = hpr_l[(size_t)m * NH + c] * sg;
            hfp_l[(size_t)m * NH + c] = val;
            hbf_l[(size_t)m * NH + c] = (bf16_t)val;
            if (l < NL - 1) {
                ob[(size_t)m * NH + c] = (bf16_t)val;
            } else {
                p.out[((size_t)m * NS + t) * NH + c] = val;   // outs (B,S,H)
            }
            if (t == NS - 1) {
                p.out[(size_t)NB * NS * NH + ((size_t)l * NB + m) * NH + c] = val;  // hT
            }
        }
    }
}

// ---------- persistent kernel: whole time loop, 6 custom barriers/step ----------
__global__ void __launch_bounds__(512, 2) fused_kernel(P p) {
    __shared__ float smem[3072];   // gru combine (12KB) / sort buf (4KB) / a3 combine (4KB)
    unsigned r = 0;
    for (int s = 0; s < NS + NL - 1; ++s) {
        st_gru(p, s, smem);   gbar(p.bar, ++r);
        st_sort(p, s, smem);  gbar(p.bar, ++r);
        st_a0(p, s);          gbar(p.bar, ++r);
        st_a1(p, s);          gbar(p.bar, ++r);
        st_a2(p, s);          gbar(p.bar, ++r);
        st_a3(p, s, smem);    gbar(p.bar, ++r);
    }
}

extern "C" void kernel_launch(void* const* d_in, const int* in_sizes, int n_in,
                              void* d_out, int out_size, void* d_ws, size_t ws_size,
                              hipStream_t stream) {
    const float* x       = (const float*)d_in[0];
    const float* hidden0 = (const float*)d_in[1];
    const float* Wih_f   = (const float*)d_in[2];
    const float* Whh_f   = (const float*)d_in[3];
    const float* bih     = (const float*)d_in[4];
    const float* bhh     = (const float*)d_in[5];
    const float* aw0     = (const float*)d_in[6];
    const float* aw1     = (const float*)d_in[7];
    const float* aw2     = (const float*)d_in[8];
    const float* aw3     = (const float*)d_in[9];

    char* ws = (char*)d_ws;
    size_t off = 0;
    auto alloc = [&](size_t bytes) -> void* {
        void* r = ws + off;
        off = (off + bytes + 255) & ~(size_t)255;
        return r;
    };

    const long nWih = (long)NL * G3H * NH;
    const long nWhh = (long)NL * G3H * NH;
    const long nw0  = (long)NL * NH * NH;
    const long nw1  = (long)NL * 512 * 512;
    const long nw2  = (long)NL * 512 * 512;
    const long nw3  = (long)NL * NH * 2048;

    P p;
    p.x = x; p.b_ih = bih; p.b_hh = bhh; p.out = (float*)d_out;
    p.Wih = (bf16_t*)alloc((size_t)nWih * 2);
    p.Whh = (bf16_t*)alloc((size_t)nWhh * 2);
    p.w0  = (bf16_t*)alloc((size_t)nw0 * 2);
    p.w1  = (bf16_t*)alloc((size_t)nw1 * 2);
    p.w2  = (bf16_t*)alloc((size_t)nw2 * 2);
    p.w3  = (bf16_t*)alloc((size_t)nw3 * 2);
    p.h_fp   = (float*) alloc((size_t)NL * NB * NH * 4);
    p.h_bf   = (bf16_t*)alloc((size_t)NL * NB * NH * 2);
    p.hprime = (float*) alloc((size_t)NL * NB * NH * 4);
    p.se     = (bf16_t*)alloc((size_t)NL * 2 * NB * NH * 2);
    p.sA0    = (bf16_t*)alloc((size_t)NL * NB * 2048 * 2);
    p.sA1    = (bf16_t*)alloc((size_t)NL * NB * 2048 * 2);
    p.a2     = (bf16_t*)alloc((size_t)NL * NB * 2048 * 2);
    p.outbuf = (bf16_t*)alloc((size_t)2 * NL * NB * NH * 2);
    p.bar    = (unsigned*)alloc(8 * 32 * sizeof(unsigned));

    ConvArgs ca;
    ca.src[0] = Wih_f; ca.dst[0] = (bf16_t*)p.Wih; ca.n[0] = nWih;
    ca.src[1] = Whh_f; ca.dst[1] = (bf16_t*)p.Whh; ca.n[1] = nWhh;
    ca.src[2] = aw0;   ca.dst[2] = (bf16_t*)p.w0;  ca.n[2] = nw0;
    ca.src[3] = aw1;   ca.dst[3] = (bf16_t*)p.w1;  ca.n[3] = nw1;
    ca.src[4] = aw2;   ca.dst[4] = (bf16_t*)p.w2;  ca.n[4] = nw2;
    ca.src[5] = aw3;   ca.dst[5] = (bf16_t*)p.w3;  ca.n[5] = nw3;
    ca.hidden0 = hidden0;
    ca.h_fp = p.h_fp;
    ca.h_bf = p.h_bf;
    ca.bar = p.bar;

    convert_kernel<<<dim3(2048), dim3(256), 0, stream>>>(ca);

    void* kargs[] = { (void*)&p };
    hipLaunchCooperativeKernel((const void*)fused_kernel, dim3(NWG), dim3(512),
                               kargs, 0, stream);
}

// Round 4
// 35393.521 us; speedup vs baseline: 2.0383x; 1.2164x over previous
//
#include <hip/hip_runtime.h>
#include <hip/hip_bf16.h>

typedef __bf16 bf16_t;
typedef bf16_t bf16x8 __attribute__((ext_vector_type(8)));
typedef float  f32x4  __attribute__((ext_vector_type(4)));

#define NB 64      // batch
#define NS 256     // seq len
#define NH 1024    // hidden
#define NL 4       // layers
#define G3H 3072   // 3*H
#define NWG 256    // workgroups in the persistent grid

__device__ __forceinline__ f32x4 mfma16(bf16x8 a, bf16x8 b, f32x4 c) {
    return __builtin_amdgcn_mfma_f32_16x16x32_bf16(a, b, c, 0, 0, 0);
}

__device__ __forceinline__ float sigmoidf_(float x) {
    return 1.0f / (1.0f + expf(-x));
}

// async global->LDS, 16B per lane; LDS dest is wave-uniform base + lane*16,
// global src is per-lane (we pre-swizzle the source so LDS stays linear).
__device__ __forceinline__ void stage16(const void* g, void* l) {
    __builtin_amdgcn_global_load_lds(
        (const __attribute__((address_space(1))) unsigned int*)g,
        (__attribute__((address_space(3))) unsigned int*)l, 16, 0, 0);
}

struct P {
    const float* x;        // (B,S,H)
    const float* b_ih;     // (L,3H)
    const float* b_hh;     // (L,3H)
    float* out;            // outs (B,S,H) then hT (L,B,H)
    const bf16_t* Wih;     // (L,3H,H)
    const bf16_t* Whh;
    const bf16_t* w0;      // (L,H,H)
    const bf16_t* w1;      // (L,512,512)
    const bf16_t* w2;      // (L,512,512)
    const bf16_t* w3;      // (L,H,2H)
    float*  h_fp;          // (L,B,H) hidden state fp32
    bf16_t* h_bf;          // (L,B,H)
    float*  hprime;        // (L,B,H) GRU output pre-attn
    bf16_t* se;            // (L,B,2,H)  row0=h', row1=sorted(h')
    bf16_t* sA0;           // (L,B,2048) shuffled a0
    bf16_t* sA1;           // (L,B,2048) shuffled a1
    bf16_t* a2;            // (L,B,2048) relu(a2) flat
    bf16_t* outbuf;        // (2,L,B,H)  inter-layer input, dbuf by t parity
    unsigned* bar;         // barrier counters: 8 cachelines (stride 32 u32)
};

struct ConvArgs {
    const float* src[6];
    bf16_t* dst[6];
    long n[6];
    const float* hidden0;  // (L,1,H)
    float* h_fp;
    bf16_t* h_bf;
    unsigned* bar;
};

__global__ void __launch_bounds__(256) convert_kernel(ConvArgs a) {
    const long tid = (long)blockIdx.x * 256 + threadIdx.x;
    const long stride = (long)gridDim.x * 256;
    if (tid < 8) a.bar[tid * 32] = 0u;   // reset barrier lines every launch/replay
    for (int i = 0; i < 6; ++i) {
        const float* s = a.src[i];
        bf16_t* d = a.dst[i];
        const long n = a.n[i];
        for (long j = tid * 4; j < n; j += stride * 4) {
            float4 v = *(const float4*)(s + j);
            d[j + 0] = (bf16_t)v.x;
            d[j + 1] = (bf16_t)v.y;
            d[j + 2] = (bf16_t)v.z;
            d[j + 3] = (bf16_t)v.w;
        }
    }
    for (long j = tid; j < (long)NL * NB * NH; j += stride) {
        int l = (int)(j >> 16);           // B*H = 65536
        int c = (int)(j & (NH - 1));
        float v = a.hidden0[l * NH + c];
        a.h_fp[j] = v;
        a.h_bf[j] = (bf16_t)v;
    }
}

// ---------- device-wide barrier: 8-line split arrival (32 WGs/line), monotonic ----------
__device__ __forceinline__ void gbar(unsigned* bar, unsigned round) {
    __syncthreads();                       // WG done; stores drained to L2
    const int tid = threadIdx.x;
    if (tid == 0) {
        __builtin_amdgcn_fence(__ATOMIC_RELEASE, "agent");   // L2 writeback
        __hip_atomic_fetch_add(bar + (blockIdx.x & 7) * 32, 1u,
                               __ATOMIC_RELAXED, __HIP_MEMORY_SCOPE_AGENT);
    }
    if (tid < 8) {
        const unsigned tgt = round * 32;   // 256 WGs / 8 lines
        while (__hip_atomic_load(bar + tid * 32, __ATOMIC_RELAXED,
                                 __HIP_MEMORY_SCOPE_AGENT) < tgt) {
            __builtin_amdgcn_s_sleep(1);
        }
        __builtin_amdgcn_fence(__ATOMIC_ACQUIRE, "agent");   // invalidate stale lines
    }
    __syncthreads();
}

// ---------- S1: GRU. waves 0-3 = ih GEMM, waves 4-7 = hh GEMM; LDS combine.
// Weights staged into LDS in 4 K-chunks of 256 (48KB/chunk: 24KB ih + 24KB hh).
// LDS row pitch 512B (32 x 16B chunks); XOR-swizzle chunk ^= (row&7).
__device__ __forceinline__ void st_gru(const P& p, int s, char* stg, float* smem) {
    const int l = blockIdx.x >> 6;
    const int t = s - l;
    if (t < 0 || t >= NS) return;
    const int wj = blockIdx.x & 63;
    const int tid = threadIdx.x;
    const int wave = tid >> 6, lane = tid & 63;
    const int half = wave >> 2, ws = wave & 3;   // half: 0=ih, 1=hh; ws = batch stripe
    const int lane15 = lane & 15, quad = lane >> 4, kq = quad * 8;

    const int c0 = wj * 16;          // hidden column block
    const int m0 = ws * 16;          // batch row stripe
    const int arow = m0 + lane15;

    const char* WihB = (const char*)(p.Wih + (size_t)l * G3H * NH);
    const char* WhhB = (const char*)(p.Whh + (size_t)l * G3H * NH);

    const bf16_t* ap = nullptr;
    const float* xrow = nullptr;
    if (half == 0) {
        if (l == 0) xrow = p.x + ((size_t)arow * NS + t) * NH;
        else ap = p.outbuf + ((size_t)(t & 1) * NL + (l - 1)) * NB * NH + (size_t)arow * NH;
    } else {
        ap = p.h_bf + (size_t)l * NB * NH + (size_t)arow * NH;
    }

    f32x4 acc0 = {}, acc1 = {}, acc2 = {};
    const int swz = lane15 & 7;
    const int tbase = half * 24576;

    for (int cc = 0; cc < 4; ++cc) {
        // stage chunk cc: 48 x 1KB instructions, 6 per wave.
        // virtual rows: ih vr 0..47 (vr = g*16+rl -> Wih row g*NH+c0+rl), then hh.
#pragma unroll
        for (int ii = 0; ii < 6; ++ii) {
            const int i = wave * 6 + ii;        // 0..47
            const int ht = (i >= 24);
            const int tb = i * 1024 + lane * 16 - ht * 24576;  // tile-local byte
            const int r = tb >> 9;              // vrow 0..47
            const int c = (tb >> 4) & 31;       // 16B chunk in row
            const int grow = (r >> 4) * NH + c0 + (r & 15);
            const char* src = (ht ? WhhB : WihB)
                + (size_t)grow * 2048 + cc * 512 + ((c ^ (r & 7)) << 4);
            stage16(src, stg + i * 1024);
        }
        asm volatile("s_waitcnt vmcnt(0)" ::: "memory");
        __syncthreads();
#pragma unroll
        for (int kk = 0; kk < 8; ++kk) {
            const int k = cc * 256 + kk * 32 + kq;
            bf16x8 a;
            if (half == 0 && l == 0) {
                float4 f0 = *(const float4*)(xrow + k);
                float4 f1 = *(const float4*)(xrow + k + 4);
                a[0] = (bf16_t)f0.x; a[1] = (bf16_t)f0.y;
                a[2] = (bf16_t)f0.z; a[3] = (bf16_t)f0.w;
                a[4] = (bf16_t)f1.x; a[5] = (bf16_t)f1.y;
                a[6] = (bf16_t)f1.z; a[7] = (bf16_t)f1.w;
            } else {
                a = *(const bf16x8*)(ap + k);
            }
            const int cx = ((kk * 4 + quad) ^ swz) << 4;
            const char* bp = stg + tbase + lane15 * 512 + cx;
            bf16x8 b0 = *(const bf16x8*)(bp);
            bf16x8 b1 = *(const bf16x8*)(bp + 8192);    // gate 1: +16 rows
            bf16x8 b2 = *(const bf16x8*)(bp + 16384);   // gate 2: +32 rows
            acc0 = mfma16(a, b0, acc0);
            acc1 = mfma16(a, b1, acc1);
            acc2 = mfma16(a, b2, acc2);
        }
        __syncthreads();   // chunk consumed by all waves before overwrite
    }

    if (half == 1) {
        // hand hh partials to the matching ih wave: layout [ws][g][lane][i]
        float* sl = smem + ws * 768 + lane * 4;
#pragma unroll
        for (int i = 0; i < 4; ++i) {
            sl[i]       = acc0[i];
            sl[256 + i] = acc1[i];
            sl[512 + i] = acc2[i];
        }
    }
    __syncthreads();
    if (half == 0) {
        const float* bih_l = p.b_ih + l * G3H;
        const float* bhh_l = p.b_hh + l * G3H;
        const float* hfp_l = p.h_fp + (size_t)l * NB * NH;
        float*  hpr_l = p.hprime + (size_t)l * NB * NH;
        bf16_t* se_l  = p.se + (size_t)l * 2 * NB * NH;
        const int c = c0 + lane15;
        const float* sl = smem + ws * 768 + lane * 4;
        const float b0 = bih_l[c], b1 = bih_l[NH + c], b2 = bih_l[2 * NH + c];
        const float d0 = bhh_l[c], d1 = bhh_l[NH + c], d2 = bhh_l[2 * NH + c];
#pragma unroll
        for (int i = 0; i < 4; ++i) {
            const int m = m0 + quad * 4 + i;
            float ir  = acc0[i] + b0;
            float iz  = acc1[i] + b1;
            float inn = acc2[i] + b2;
            float hr  = sl[i]       + d0;
            float hz  = sl[256 + i] + d1;
            float hn  = sl[512 + i] + d2;
            float r = sigmoidf_(ir + hr);
            float z = sigmoidf_(iz + hz);
            float n = tanhf(inn + r * hn);
            float hprev = hfp_l[(size_t)m * NH + c];
            float hp = (1.0f - z) * n + z * hprev;
            hpr_l[(size_t)m * NH + c] = hp;
            se_l[(size_t)(m * 2) * NH + c] = (bf16_t)hp;   // se row 0 = h'
        }
    }
}

// ---------- S2: sort h' rows (bitonic ascending) -> se row 1. 512 threads ----------
__device__ __forceinline__ void st_sort(const P& p, int s, float* smem) {
    const int l = blockIdx.x >> 6;
    const int t = s - l;
    if (t < 0 || t >= NS) return;
    const int b = blockIdx.x & 63;
    const int tid = threadIdx.x;
    const float* src = p.hprime + (size_t)l * NB * NH + (size_t)b * NH;
    for (int i = tid; i < NH; i += 512) smem[i] = src[i];
    __syncthreads();
    for (int kk = 2; kk <= NH; kk <<= 1) {
        for (int j = kk >> 1; j > 0; j >>= 1) {
#pragma unroll
            for (int bb = 0; bb < 2; ++bb) {
                const int i = bb * 512 + tid;
                const int ixj = i ^ j;
                if (ixj > i) {
                    float va = smem[i], vb = smem[ixj];
                    bool up = ((i & kk) == 0);
                    if (up ? (va > vb) : (va < vb)) {
                        smem[i] = vb; smem[ixj] = va;
                    }
                }
            }
            __syncthreads();
        }
    }
    bf16_t* dst = p.se + (size_t)l * 2 * NB * NH + (size_t)(b * 2 + 1) * NH;
    for (int i = tid; i < NH; i += 512) dst[i] = (bf16_t)smem[i];
}

// ---------- S3: a0 = se@w0^T (M=128,N=1024,K=1024). 8 waves cover all 128 rows.
// w0 tile (16 rows x 2KB = 32KB) staged once; pitch 2KB (128 chunks). ----------
__device__ __forceinline__ void st_a0(const P& p, int s, char* stg) {
    const int l = blockIdx.x >> 6;
    const int t = s - l;
    if (t < 0 || t >= NS) return;
    const int cj = blockIdx.x & 63;      // 64 col jobs of 16
    const int tid = threadIdx.x;
    const int wave = tid >> 6, lane = tid & 63;
    const int lane15 = lane & 15, quad = lane >> 4, kq = quad * 8;
    const char* w0B = (const char*)(p.w0 + (size_t)l * NH * NH);
    const bf16_t* se_l = p.se + (size_t)l * 2 * NB * NH;
    bf16_t* sA0_l = p.sA0 + (size_t)l * NB * 2048;

    const int c0 = cj * 16;
    const int r0 = wave * 16;            // 8 waves x 16 = 128 rows
#pragma unroll
    for (int ii = 0; ii < 4; ++ii) {
        const int i = wave * 4 + ii;     // 0..31
        const int tb = i * 1024 + lane * 16;
        const int r = tb >> 11, c = (tb >> 4) & 127;
        stage16(w0B + (size_t)(c0 + r) * 2048 + ((c ^ (r & 7)) << 4), stg + i * 1024);
    }
    asm volatile("s_waitcnt vmcnt(0)" ::: "memory");
    __syncthreads();
    const bf16_t* arow = se_l + (size_t)(r0 + lane15) * NH;
    const int swz = lane15 & 7;
    f32x4 acc = {};
#pragma unroll
    for (int kk = 0; kk < 32; ++kk) {
        bf16x8 a = *(const bf16x8*)(arow + kk * 32 + kq);
        bf16x8 b = *(const bf16x8*)(stg + lane15 * 2048 + (((kk * 4 + quad) ^ swz) << 4));
        acc = mfma16(a, b, acc);
    }
#pragma unroll
    for (int i = 0; i < 4; ++i) {
        const int r = r0 + quad * 4 + i;   // 0..127 = b*2+tt
        const int bidx = r >> 1, tt = r & 1;
        const int j0 = tt * NH + c0 + lane15;
        sA0_l[(size_t)bidx * 2048 + ((j0 & 511) * 4 + (j0 >> 9))] = (bf16_t)acc[i];
    }
}

// ---------- S4: a1 = sA0@w1^T (M=256,N=512,K=512). w1 tile 16KB staged; pitch 1KB ----------
__device__ __forceinline__ void st_a1(const P& p, int s, char* stg) {
    const int l = blockIdx.x >> 6;
    const int t = s - l;
    if (t < 0 || t >= NS) return;
    const int wj = blockIdx.x & 63;
    const int tid = threadIdx.x;
    const int wave = tid >> 6, lane = tid & 63;
    const int lane15 = lane & 15, quad = lane >> 4, kq = quad * 8;
    const char* w1B = (const char*)(p.w1 + (size_t)l * 512 * 512);
    const bf16_t* sA0_l = p.sA0 + (size_t)l * NB * 2048;
    bf16_t* sA1_l = p.sA1 + (size_t)l * NB * 2048;

    const int mhalf = wj >> 5;           // 0..1 -> rows 0-127 / 128-255
    const int c0 = (wj & 31) * 16;       // 32 col jobs of 16
    const int r0 = mhalf * 128 + wave * 16;
#pragma unroll
    for (int ii = 0; ii < 2; ++ii) {
        const int i = wave * 2 + ii;     // 0..15
        const int tb = i * 1024 + lane * 16;
        const int r = tb >> 10, c = (tb >> 4) & 63;
        stage16(w1B + (size_t)(c0 + r) * 1024 + ((c ^ (r & 7)) << 4), stg + i * 1024);
    }
    asm volatile("s_waitcnt vmcnt(0)" ::: "memory");
    __syncthreads();
    const bf16_t* arow = sA0_l + (size_t)(r0 + lane15) * 512;
    const int swz = lane15 & 7;
    f32x4 acc = {};
#pragma unroll
    for (int kk = 0; kk < 16; ++kk) {
        bf16x8 a = *(const bf16x8*)(arow + kk * 32 + kq);
        bf16x8 b = *(const bf16x8*)(stg + lane15 * 1024 + (((kk * 4 + quad) ^ swz) << 4));
        acc = mfma16(a, b, acc);
    }
#pragma unroll
    for (int i = 0; i < 4; ++i) {
        const int rr = r0 + quad * 4 + i;
        const int bidx = rr >> 2, g = rr & 3;
        const int o0 = c0 + lane15;
        sA1_l[(size_t)bidx * 2048 + o0 * 4 + g] = (bf16_t)acc[i];
    }
}

// ---------- S5: a2 = relu(sA1@w2^T), store flat. Same staging as S4 ----------
__device__ __forceinline__ void st_a2(const P& p, int s, char* stg) {
    const int l = blockIdx.x >> 6;
    const int t = s - l;
    if (t < 0 || t >= NS) return;
    const int wj = blockIdx.x & 63;
    const int tid = threadIdx.x;
    const int wave = tid >> 6, lane = tid & 63;
    const int lane15 = lane & 15, quad = lane >> 4, kq = quad * 8;
    const char* w2B = (const char*)(p.w2 + (size_t)l * 512 * 512);
    const bf16_t* sA1_l = p.sA1 + (size_t)l * NB * 2048;
    bf16_t* a2_l = p.a2 + (size_t)l * NB * 2048;

    const int mhalf = wj >> 5;
    const int c0 = (wj & 31) * 16;
    const int r0 = mhalf * 128 + wave * 16;
#pragma unroll
    for (int ii = 0; ii < 2; ++ii) {
        const int i = wave * 2 + ii;
        const int tb = i * 1024 + lane * 16;
        const int r = tb >> 10, c = (tb >> 4) & 63;
        stage16(w2B + (size_t)(c0 + r) * 1024 + ((c ^ (r & 7)) << 4), stg + i * 1024);
    }
    asm volatile("s_waitcnt vmcnt(0)" ::: "memory");
    __syncthreads();
    const bf16_t* arow = sA1_l + (size_t)(r0 + lane15) * 512;
    const int swz = lane15 & 7;
    f32x4 acc = {};
#pragma unroll
    for (int kk = 0; kk < 16; ++kk) {
        bf16x8 a = *(const bf16x8*)(arow + kk * 32 + kq);
        bf16x8 b = *(const bf16x8*)(stg + lane15 * 1024 + (((kk * 4 + quad) ^ swz) << 4));
        acc = mfma16(a, b, acc);
    }
#pragma unroll
    for (int i = 0; i < 4; ++i) {
        const int rr = r0 + quad * 4 + i;       // b*4+g
        const int o0 = c0 + lane15;
        float v = acc[i] > 0.0f ? acc[i] : 0.0f;
        a2_l[(size_t)rr * 512 + o0] = (bf16_t)v;
    }
}

// ---------- S6: a3 = a2@w3^T (M=64,N=1024,K=2048). Two serial K-halves, each
// staged as 32KB (16 rows x 2KB); waves 0-3 accumulate both halves in registers.
// h = h'*sigmoid(a3). ----------
__device__ __forceinline__ void st_a3(const P& p, int s, char* stg) {
    const int l = blockIdx.x >> 6;
    const int t = s - l;
    if (t < 0 || t >= NS) return;
    const int wj = blockIdx.x & 63;
    const int tid = threadIdx.x;
    const int wave = tid >> 6, lane = tid & 63;
    const int ws = wave & 3;
    const int lane15 = lane & 15, quad = lane >> 4, kq = quad * 8;
    const char* w3B = (const char*)(p.w3 + (size_t)l * NH * 2048);
    const bf16_t* a2_l = p.a2 + (size_t)l * NB * 2048;

    const int c0 = wj * 16;
    const int m0 = ws * 16;
    const bf16_t* arow = a2_l + (size_t)(m0 + lane15) * 2048;
    const int swz = lane15 & 7;
    f32x4 acc = {};

    for (int hf = 0; hf < 2; ++hf) {
#pragma unroll
        for (int ii = 0; ii < 4; ++ii) {
            const int i = wave * 4 + ii;     // 0..31
            const int tb = i * 1024 + lane * 16;
            const int r = tb >> 11, c = (tb >> 4) & 127;
            stage16(w3B + (size_t)(c0 + r) * 4096 + hf * 2048 + ((c ^ (r & 7)) << 4),
                    stg + i * 1024);
        }
        asm volatile("s_waitcnt vmcnt(0)" ::: "memory");
        __syncthreads();
        if (wave < 4) {
#pragma unroll
            for (int kk = 0; kk < 32; ++kk) {
                bf16x8 a = *(const bf16x8*)(arow + hf * 1024 + kk * 32 + kq);
                bf16x8 b = *(const bf16x8*)(stg + lane15 * 2048
                                            + (((kk * 4 + quad) ^ swz) << 4));
                acc = mfma16(a, b, acc);
            }
        }
        __syncthreads();
    }

    if (wave < 4) {
        const float* hpr_l = p.hprime + (size_t)l * NB * NH;
        float*  hfp_l = p.h_fp + (size_t)l * NB * NH;
        bf16_t* hbf_l = p.h_bf + (size_t)l * NB * NH;
        const int c = c0 + lane15;
        bf16_t* ob = (l < NL - 1)
            ? (p.outbuf + ((size_t)(t & 1) * NL + l) * NB * NH) : nullptr;
#pragma unroll
        for (int i = 0; i < 4; ++i) {
            const int m = m0 + quad * 4 + i;
            float sg = sigmoidf_(acc[i]);
            float val = hpr_l[(size_t)m * NH + c] * sg;
            hfp_l[(size_t)m * NH + c] = val;
            hbf_l[(size_t)m * NH + c] = (bf16_t)val;
            if (l < NL - 1) {
                ob[(size_t)m * NH + c] = (bf16_t)val;
            } else {
                p.out[((size_t)m * NS + t) * NH + c] = val;   // outs (B,S,H)
            }
            if (t == NS - 1) {
                p.out[(size_t)NB * NS * NH + ((size_t)l * NB + m) * NH + c] = val;  // hT
            }
        }
    }
}

// ---------- persistent kernel: whole time loop, 6 custom barriers/step ----------
__global__ void __launch_bounds__(512, 2) fused_kernel(P p) {
    __shared__ __align__(16) char stg[49152];   // weight staging (LDS-DMA dest)
    __shared__ float smem[3072];                // gru combine (12KB) / sort buf (4KB)
    unsigned r = 0;
    for (int s = 0; s < NS + NL - 1; ++s) {
        st_gru(p, s, stg, smem);  gbar(p.bar, ++r);
        st_sort(p, s, smem);      gbar(p.bar, ++r);
        st_a0(p, s, stg);         gbar(p.bar, ++r);
        st_a1(p, s, stg);         gbar(p.bar, ++r);
        st_a2(p, s, stg);         gbar(p.bar, ++r);
        st_a3(p, s, stg);         gbar(p.bar, ++r);
    }
}

extern "C" void kernel_launch(void* const* d_in, const int* in_sizes, int n_in,
                              void* d_out, int out_size, void* d_ws, size_t ws_size,
                              hipStream_t stream) {
    const float* x       = (const float*)d_in[0];
    const float* hidden0 = (const float*)d_in[1];
    const float* Wih_f   = (const float*)d_in[2];
    const float* Whh_f   = (const float*)d_in[3];
    const float* bih     = (const float*)d_in[4];
    const float* bhh     = (const float*)d_in[5];
    const float* aw0     = (const float*)d_in[6];
    const float* aw1     = (const float*)d_in[7];
    const float* aw2     = (const float*)d_in[8];
    const float* aw3     = (const float*)d_in[9];

    char* ws = (char*)d_ws;
    size_t off = 0;
    auto alloc = [&](size_t bytes) -> void* {
        void* r = ws + off;
        off = (off + bytes + 255) & ~(size_t)255;
        return r;
    };

    const long nWih = (long)NL * G3H * NH;
    const long nWhh = (long)NL * G3H * NH;
    const long nw0  = (long)NL * NH * NH;
    const long nw1  = (long)NL * 512 * 512;
    const long nw2  = (long)NL * 512 * 512;
    const long nw3  = (long)NL * NH * 2048;

    P p;
    p.x = x; p.b_ih = bih; p.b_hh = bhh; p.out = (float*)d_out;
    p.Wih = (bf16_t*)alloc((size_t)nWih * 2);
    p.Whh = (bf16_t*)alloc((size_t)nWhh * 2);
    p.w0  = (bf16_t*)alloc((size_t)nw0 * 2);
    p.w1  = (bf16_t*)alloc((size_t)nw1 * 2);
    p.w2  = (bf16_t*)alloc((size_t)nw2 * 2);
    p.w3  = (bf16_t*)alloc((size_t)nw3 * 2);
    p.h_fp   = (float*) alloc((size_t)NL * NB * NH * 4);
    p.h_bf   = (bf16_t*)alloc((size_t)NL * NB * NH * 2);
    p.hprime = (float*) alloc((size_t)NL * NB * NH * 4);
    p.se     = (bf16_t*)alloc((size_t)NL * 2 * NB * NH * 2);
    p.sA0    = (bf16_t*)alloc((size_t)NL * NB * 2048 * 2);
    p.sA1    = (bf16_t*)alloc((size_t)NL * NB * 2048 * 2);
    p.a2     = (bf16_t*)alloc((size_t)NL * NB * 2048 * 2);
    p.outbuf = (bf16_t*)alloc((size_t)2 * NL * NB * NH * 2);
    p.bar    = (unsigned*)alloc(8 * 32 * sizeof(unsigned));

    ConvArgs ca;
    ca.src[0] = Wih_f; ca.dst[0] = (bf16_t*)p.Wih; ca.n[0] = nWih;
    ca.src[1] = Whh_f; ca.dst[1] = (bf16_t*)p.Whh; ca.n[1] = nWhh;
    ca.src[2] = aw0;   ca.dst[2] = (bf16_t*)p.w0;  ca.n[2] = nw0;
    ca.src[3] = aw1;   ca.dst[3] = (bf16_t*)p.w1;  ca.n[3] = nw1;
    ca.src[4] = aw2;   ca.dst[4] = (bf16_t*)p.w2;  ca.n[4] = nw2;
    ca.src[5] = aw3;   ca.dst[5] = (bf16_t*)p.w3;  ca.n[5] = nw3;
    ca.hidden0 = hidden0;
    ca.h_fp = p.h_fp;
    ca.h_bf = p.h_bf;
    ca.bar = p.bar;

    convert_kernel<<<dim3(2048), dim3(256), 0, stream>>>(ca);

    void* kargs[] = { (void*)&p };
    hipLaunchCooperativeKernel((const void*)fused_kernel, dim3(NWG), dim3(512),
                               kargs, 0, stream);
}